// Round 1
// baseline (725.892 us; speedup 1.0000x reference)
//
#include <hip/hip_runtime.h>
#include <cstddef>
#include <math.h>

#define D_MODEL 256
#define NHEAD 4
#define HEAD_DIM 64
#define BSZ 2
#define SEQ 2048
#define MROWS (BSZ * SEQ) /* 4096 */

// ---------------------------------------------------------------------------
// Templated tiled GEMM: C[M x N] = op(A)[M x K] @ B[K x N], optional ReLU.
// AMODE 0: A = A1 (row stride lda)
// AMODE 1: A = A1 + A2 (elementwise, both stride lda)         [x + pe fusion]
// AMODE 2: A = concat(A1, A2) along k (each stride 256)       [concat fusion]
// Block: 256 threads, 64x64 tile, BK=16, each thread 4x4 micro-tile.
// ---------------------------------------------------------------------------
template <int AMODE, bool RELU>
__global__ __launch_bounds__(256) void gemm_k(
    const float* __restrict__ A1, const float* __restrict__ A2,
    const float* __restrict__ B, float* __restrict__ C,
    int Kdim, int Ndim, int lda)
{
    __shared__ __attribute__((aligned(16))) float As[16][68];  // [k][m], pad 68
    __shared__ __attribute__((aligned(16))) float Bs[16][64];  // [k][n]

    const int t  = threadIdx.x;
    const int tx = t & 15, ty = t >> 4;
    const int m0 = blockIdx.y * 64, n0 = blockIdx.x * 64;

    const int mA  = t >> 2;          // 0..63
    const int k4A = (t & 3) * 4;     // 0,4,8,12
    const int kB  = t >> 4;          // 0..15
    const int n4B = (t & 15) * 4;    // 0..60

    float acc[4][4] = {};

    for (int k0 = 0; k0 < Kdim; k0 += 16) {
        // global -> regs
        float4 va;
        if (AMODE == 1) {
            float4 a = *(const float4*)&A1[(size_t)(m0 + mA) * lda + k0 + k4A];
            float4 b = *(const float4*)&A2[(size_t)(m0 + mA) * lda + k0 + k4A];
            va = make_float4(a.x + b.x, a.y + b.y, a.z + b.z, a.w + b.w);
        } else if (AMODE == 2) {
            const float* P = (k0 < 256) ? A1 : A2;
            const int c = (k0 < 256) ? (k0 + k4A) : (k0 - 256 + k4A);
            va = *(const float4*)&P[(size_t)(m0 + mA) * 256 + c];
        } else {
            va = *(const float4*)&A1[(size_t)(m0 + mA) * lda + k0 + k4A];
        }
        float4 vb = *(const float4*)&B[(size_t)(k0 + kB) * Ndim + n0 + n4B];

        __syncthreads();  // previous tile's compute done
        As[k4A + 0][mA] = va.x;
        As[k4A + 1][mA] = va.y;
        As[k4A + 2][mA] = va.z;
        As[k4A + 3][mA] = va.w;
        *(float4*)&Bs[kB][n4B] = vb;
        __syncthreads();

#pragma unroll
        for (int k = 0; k < 16; k++) {
            const float4 a = *(const float4*)&As[k][ty * 4];
            const float4 b = *(const float4*)&Bs[k][tx * 4];
            const float av[4] = {a.x, a.y, a.z, a.w};
            const float bv[4] = {b.x, b.y, b.z, b.w};
#pragma unroll
            for (int i = 0; i < 4; i++)
#pragma unroll
                for (int j = 0; j < 4; j++) acc[i][j] += av[i] * bv[j];
        }
    }

#pragma unroll
    for (int i = 0; i < 4; i++) {
        const int m = m0 + ty * 4 + i;
#pragma unroll
        for (int j = 0; j < 4; j++) {
            float v = acc[i][j];
            if (RELU) v = fmaxf(v, 0.f);
            C[(size_t)m * Ndim + n0 + tx * 4 + j] = v;
        }
    }
}

// ---------------------------------------------------------------------------
// Flash-style attention. Grid: (SEQ/32, NHEAD, BSZ), block 256.
// Q/K/V stored (4096, 256) with col = h*64 + d.
// scores = (q.k) * comp(l,s) / 8; masked (x_mask[l] && !source_mask[s]) -> -1e30
// Online softmax over S; per-thread: 1 q-row (rq=t>>3) x 8 cols (cg + 8*jj).
// LDS stride 68 keeps float4 reads <=2-way bank aliased (free per m136).
// ---------------------------------------------------------------------------
__global__ __launch_bounds__(256) void attn_k(
    const float* __restrict__ Q, const float* __restrict__ K,
    const float* __restrict__ V, const float* __restrict__ comp,
    const int* __restrict__ xmask, const int* __restrict__ smask,
    float* __restrict__ O)
{
    __shared__ __attribute__((aligned(16))) float Qs[32][68];
    __shared__ __attribute__((aligned(16))) float Ks[64][68];
    __shared__ __attribute__((aligned(16))) float Vs[64][68];
    __shared__ __attribute__((aligned(16))) float Cs[32][68];
    __shared__ __attribute__((aligned(16))) float Ps[32][68];
    __shared__ int xms[32];
    __shared__ int sms[64];

    const int t  = threadIdx.x;
    const int l0 = blockIdx.x * 32;
    const int h  = blockIdx.y, b = blockIdx.z;
    const int rq = t >> 3, cg = t & 7, d0 = cg * 8;

#pragma unroll
    for (int i = 0; i < 2; i++) {
        const int e = t + i * 256, r = e >> 4, c = (e & 15) * 4;
        const float4 v = *(const float4*)&Q[((size_t)(b * SEQ + l0 + r)) * D_MODEL + h * HEAD_DIM + c];
        Qs[r][c] = v.x; Qs[r][c + 1] = v.y; Qs[r][c + 2] = v.z; Qs[r][c + 3] = v.w;
    }
    if (t < 32) xms[t] = xmask[b * SEQ + l0 + t];

    float m_i = -INFINITY, l_i = 0.f;
    float acc[8] = {0, 0, 0, 0, 0, 0, 0, 0};

    for (int s0 = 0; s0 < SEQ; s0 += 64) {
        __syncthreads();  // previous tile fully consumed
#pragma unroll
        for (int i = 0; i < 4; i++) {
            const int e = t + i * 256, r = e >> 4, c = (e & 15) * 4;
            const float4 kv = *(const float4*)&K[((size_t)(b * SEQ + s0 + r)) * D_MODEL + h * HEAD_DIM + c];
            Ks[r][c] = kv.x; Ks[r][c + 1] = kv.y; Ks[r][c + 2] = kv.z; Ks[r][c + 3] = kv.w;
            const float4 vv = *(const float4*)&V[((size_t)(b * SEQ + s0 + r)) * D_MODEL + h * HEAD_DIM + c];
            Vs[r][c] = vv.x; Vs[r][c + 1] = vv.y; Vs[r][c + 2] = vv.z; Vs[r][c + 3] = vv.w;
        }
#pragma unroll
        for (int i = 0; i < 2; i++) {
            const int e = t + i * 256, r = e >> 4, c = (e & 15) * 4;
            const float4 cv = *(const float4*)&comp[((size_t)(b * SEQ) + l0 + r) * SEQ + s0 + c];
            Cs[r][c] = cv.x; Cs[r][c + 1] = cv.y; Cs[r][c + 2] = cv.z; Cs[r][c + 3] = cv.w;
        }
        if (t < 64) sms[t] = smask[b * SEQ + s0 + t];
        __syncthreads();

        // QK^T : 8 cols per thread, col = cg + 8*jj (interleaved -> no LDS conflict)
        float dacc[8] = {0, 0, 0, 0, 0, 0, 0, 0};
#pragma unroll
        for (int k4 = 0; k4 < 16; k4++) {
            const float4 q = *(const float4*)&Qs[rq][k4 * 4];
#pragma unroll
            for (int jj = 0; jj < 8; jj++) {
                const float4 kk = *(const float4*)&Ks[cg + 8 * jj][k4 * 4];
                dacc[jj] += q.x * kk.x + q.y * kk.y + q.z * kk.z + q.w * kk.w;
            }
        }

        const bool xm = (xms[rq] != 0);
        float tmax = -INFINITY;
        float sreg[8];
#pragma unroll
        for (int jj = 0; jj < 8; jj++) {
            const int col = cg + 8 * jj;
            float sc = dacc[jj] * Cs[rq][col] * 0.125f;
            if (xm && (sms[col] == 0)) sc = -1e30f;
            sreg[jj] = sc;
            tmax = fmaxf(tmax, sc);
        }
#pragma unroll
        for (int off = 1; off < 8; off <<= 1)
            tmax = fmaxf(tmax, __shfl_xor(tmax, off, 64));

        const float m_new = fmaxf(m_i, tmax);
        const float alpha = __expf(m_i - m_new);  // exp(-inf)=0 on first tile
        float psum = 0.f;
#pragma unroll
        for (int jj = 0; jj < 8; jj++) {
            const float p = __expf(sreg[jj] - m_new);
            psum += p;
            Ps[rq][cg + 8 * jj] = p;
        }
#pragma unroll
        for (int off = 1; off < 8; off <<= 1)
            psum += __shfl_xor(psum, off, 64);
        l_i = l_i * alpha + psum;
        m_i = m_new;
#pragma unroll
        for (int dd = 0; dd < 8; dd++) acc[dd] *= alpha;

        __syncthreads();  // cheap insurance: P row fully visible before PV

        // PV: thread owns row rq, dims d0..d0+7
#pragma unroll
        for (int ss = 0; ss < 64; ss++) {
            const float p  = Ps[rq][ss];
            const float4 v0 = *(const float4*)&Vs[ss][d0];
            const float4 v1 = *(const float4*)&Vs[ss][d0 + 4];
            acc[0] += p * v0.x; acc[1] += p * v0.y; acc[2] += p * v0.z; acc[3] += p * v0.w;
            acc[4] += p * v1.x; acc[5] += p * v1.y; acc[6] += p * v1.z; acc[7] += p * v1.w;
        }
    }

    const float inv = 1.f / l_i;
#pragma unroll
    for (int dd = 0; dd < 8; dd++)
        O[((size_t)(b * SEQ + l0 + rq)) * D_MODEL + h * HEAD_DIM + d0 + dd] = acc[dd] * inv;
}

// ---------------------------------------------------------------------------
// LayerNorm over rows of 256. Block 256 = one row. Optional residual add.
// ---------------------------------------------------------------------------
template <bool RESID>
__global__ __launch_bounds__(256) void ln_k(
    const float* __restrict__ in, const float* __restrict__ g,
    const float* __restrict__ bta, const float* __restrict__ resid,
    float* __restrict__ out)
{
    const int row = blockIdx.x, t = threadIdx.x;
    const float v = in[(size_t)row * 256 + t];
    float s = v, s2 = v * v;
#pragma unroll
    for (int off = 1; off < 64; off <<= 1) {
        s  += __shfl_xor(s, off, 64);
        s2 += __shfl_xor(s2, off, 64);
    }
    __shared__ float red[2][4];
    const int w = t >> 6, ln = t & 63;
    if (ln == 0) { red[0][w] = s; red[1][w] = s2; }
    __syncthreads();
    s  = red[0][0] + red[0][1] + red[0][2] + red[0][3];
    s2 = red[1][0] + red[1][1] + red[1][2] + red[1][3];
    const float mu  = s * (1.f / 256.f);
    const float var = s2 * (1.f / 256.f) - mu * mu;
    const float r   = rsqrtf(var + 1e-5f);
    float o = (v - mu) * r * g[t] + bta[t];
    if (RESID) o += resid[(size_t)row * 256 + t];
    out[(size_t)row * 256 + t] = o;
}

// ---------------------------------------------------------------------------
extern "C" void kernel_launch(void* const* d_in, const int* in_sizes, int n_in,
                              void* d_out, int out_size, void* d_ws, size_t ws_size,
                              hipStream_t stream)
{
    (void)in_sizes; (void)n_in; (void)out_size; (void)ws_size;
    const float* x      = (const float*)d_in[0];
    const float* source = (const float*)d_in[1];
    const float* x_pe   = (const float*)d_in[2];
    const float* s_pe   = (const float*)d_in[3];
    const int*   x_mask = (const int*)d_in[4];
    const int*   s_mask = (const int*)d_in[5];
    const float* comp   = (const float*)d_in[6];
    const float* Wq     = (const float*)d_in[7];
    const float* Wk     = (const float*)d_in[8];
    const float* Wv     = (const float*)d_in[9];
    const float* Wmerge = (const float*)d_in[10];
    const float* Wmlp1  = (const float*)d_in[11];
    const float* Wmlp2  = (const float*)d_in[12];
    const float* ln1_g  = (const float*)d_in[13];
    const float* ln1_b  = (const float*)d_in[14];
    const float* ln2_g  = (const float*)d_in[15];
    const float* ln2_b  = (const float*)d_in[16];
    float* out = (float*)d_out;
    float* ws  = (float*)d_ws;

    const size_t SZ = (size_t)MROWS * D_MODEL;  // 1,048,576 floats
    float* Qb = ws;             // [0, SZ)
    float* Kb = ws + SZ;        // [SZ, 2SZ)
    float* Vb = ws + 2 * SZ;    // [2SZ, 3SZ)
    float* Ob = ws + 3 * SZ;    // [3SZ, 4SZ)
    float* Mg = ws + 4 * SZ;    // [4SZ, 5SZ)
    float* Msg1 = Qb;           // reuse (Q dead after attention)
    float* H    = Kb;           // reuse K+V slots (2*SZ floats)
    float* M2   = Ob;           // reuse (O dead after merge GEMM)

    const dim3 g256(D_MODEL / 64, MROWS / 64);  // (4, 64)
    const dim3 g512(512 / 64, MROWS / 64);      // (8, 64)

    gemm_k<1, false><<<g256, 256, 0, stream>>>(x, x_pe, Wq, Qb, 256, 256, 256);
    gemm_k<1, false><<<g256, 256, 0, stream>>>(source, s_pe, Wk, Kb, 256, 256, 256);
    gemm_k<0, false><<<g256, 256, 0, stream>>>(source, nullptr, Wv, Vb, 256, 256, 256);

    attn_k<<<dim3(SEQ / 32, NHEAD, BSZ), 256, 0, stream>>>(Qb, Kb, Vb, comp, x_mask, s_mask, Ob);

    gemm_k<0, false><<<g256, 256, 0, stream>>>(Ob, nullptr, Wmerge, Mg, 256, 256, 256);
    ln_k<false><<<MROWS, 256, 0, stream>>>(Mg, ln1_g, ln1_b, nullptr, Msg1);
    gemm_k<2, true><<<g512, 256, 0, stream>>>(x, Msg1, Wmlp1, H, 512, 512, 256);
    gemm_k<0, false><<<g256, 256, 0, stream>>>(H, nullptr, Wmlp2, M2, 512, 256, 512);
    ln_k<true><<<MROWS, 256, 0, stream>>>(M2, ln2_g, ln2_b, x, out);
}

// Round 2
// 321.302 us; speedup vs baseline: 2.2592x; 2.2592x over previous
//
#include <hip/hip_runtime.h>
#include <hip/hip_bf16.h>
#include <cstddef>
#include <math.h>

#define D_MODEL 256
#define NHEAD 4
#define HEAD_DIM 64
#define BSZ 2
#define SEQ 2048
#define MROWS (BSZ * SEQ) /* 4096 */

typedef __attribute__((ext_vector_type(8))) short short8;   // 8 bf16 = 4 VGPRs
typedef __attribute__((ext_vector_type(4))) float f32x4;    // MFMA C/D

__device__ __forceinline__ ushort f2bf_bits(float f) {
    union { float f; unsigned u; } c; c.f = f;
    unsigned u = c.u + 0x7fffu + ((c.u >> 16) & 1u);  // RNE
    return (ushort)(u >> 16);
}

// ---------------------------------------------------------------------------
// Tiled fp32 vector GEMM: C[M x N] = op(A)[M x K] @ B[K x N], optional ReLU.
// AMODE 0: A = A1            1: A = A1 + A2           2: A = concat(A1,A2)
// OMODE 0: fp32 row-major    1: bf16 row-major        2: bf16 V-transposed
//   (OMODE 2: out[(b*256 + n)*2048 + s], m = b*2048 + s  -> Vt[b,h,d,s])
// ---------------------------------------------------------------------------
template <int AMODE, bool RELU, int OMODE>
__global__ __launch_bounds__(256) void gemm_k(
    const float* __restrict__ A1, const float* __restrict__ A2,
    const float* __restrict__ B, void* __restrict__ Cout,
    int Kdim, int Ndim, int lda)
{
    __shared__ __attribute__((aligned(16))) float As[16][68];
    __shared__ __attribute__((aligned(16))) float Bs[16][64];

    const int t  = threadIdx.x;
    const int tx = t & 15, ty = t >> 4;
    const int m0 = blockIdx.y * 64, n0 = blockIdx.x * 64;

    const int mA  = t >> 2;
    const int k4A = (t & 3) * 4;
    const int kB  = t >> 4;
    const int n4B = (t & 15) * 4;

    float acc[4][4] = {};

    for (int k0 = 0; k0 < Kdim; k0 += 16) {
        float4 va;
        if (AMODE == 1) {
            float4 a = *(const float4*)&A1[(size_t)(m0 + mA) * lda + k0 + k4A];
            float4 b = *(const float4*)&A2[(size_t)(m0 + mA) * lda + k0 + k4A];
            va = make_float4(a.x + b.x, a.y + b.y, a.z + b.z, a.w + b.w);
        } else if (AMODE == 2) {
            const float* P = (k0 < 256) ? A1 : A2;
            const int c = (k0 < 256) ? (k0 + k4A) : (k0 - 256 + k4A);
            va = *(const float4*)&P[(size_t)(m0 + mA) * 256 + c];
        } else {
            va = *(const float4*)&A1[(size_t)(m0 + mA) * lda + k0 + k4A];
        }
        float4 vb = *(const float4*)&B[(size_t)(k0 + kB) * Ndim + n0 + n4B];

        __syncthreads();
        As[k4A + 0][mA] = va.x;
        As[k4A + 1][mA] = va.y;
        As[k4A + 2][mA] = va.z;
        As[k4A + 3][mA] = va.w;
        *(float4*)&Bs[kB][n4B] = vb;
        __syncthreads();

#pragma unroll
        for (int k = 0; k < 16; k++) {
            const float4 a = *(const float4*)&As[k][ty * 4];
            const float4 b = *(const float4*)&Bs[k][tx * 4];
            const float av[4] = {a.x, a.y, a.z, a.w};
            const float bv[4] = {b.x, b.y, b.z, b.w};
#pragma unroll
            for (int i = 0; i < 4; i++)
#pragma unroll
                for (int j = 0; j < 4; j++) acc[i][j] += av[i] * bv[j];
        }
    }

#pragma unroll
    for (int i = 0; i < 4; i++) {
        const int m = m0 + ty * 4 + i;
#pragma unroll
        for (int j = 0; j < 4; j++) {
            const int n = n0 + tx * 4 + j;
            float v = acc[i][j];
            if (RELU) v = fmaxf(v, 0.f);
            if (OMODE == 0) {
                ((float*)Cout)[(size_t)m * Ndim + n] = v;
            } else if (OMODE == 1) {
                ((ushort*)Cout)[(size_t)m * Ndim + n] = f2bf_bits(v);
            } else {
                const int b = m >> 11, s = m & 2047;
                ((ushort*)Cout)[((size_t)(b * 256 + n)) * 2048 + s] = f2bf_bits(v);
            }
        }
    }
}

// ---------------------------------------------------------------------------
// MFMA flash attention. Grid (SEQ/64, NHEAD, BSZ), block 256 (4 waves).
// Wave w owns Q rows [w*16, w*16+16). 64-key tiles over S, online softmax.
// Q/K bf16 row-major (4096,256); Vt bf16 (b*256 + h*64 + d, s).
// scores = (q.k)*comp/8, mask (x_mask && !source_mask) -> -1e30.
// MFMA layouts (HW-verified): A[m=lane&15][k=quad*8+j]; B[k=quad*8+j][n=lane&15];
// C/D col=lane&15, row=quad*4+reg.
// ---------------------------------------------------------------------------
__global__ __launch_bounds__(256) void attn_k(
    const ushort* __restrict__ Q, const ushort* __restrict__ K,
    const ushort* __restrict__ Vt, const float* __restrict__ comp,
    const int* __restrict__ xmask, const int* __restrict__ smask,
    float* __restrict__ O)
{
    __shared__ __attribute__((aligned(16))) ushort Qs[64][72];
    __shared__ __attribute__((aligned(16))) ushort Ks[64][72];
    __shared__ __attribute__((aligned(16))) ushort Vs[64][72];   // [d][key]
    __shared__ __attribute__((aligned(16))) ushort Ps[64][72];
    __shared__ __attribute__((aligned(16))) float  Cs[64][68];
    __shared__ int xms[64];
    __shared__ int sms[64];

    const int t    = threadIdx.x;
    const int w    = t >> 6;
    const int lane = t & 63;
    const int quad = lane >> 4;
    const int l16  = lane & 15;
    const int l0   = blockIdx.x * 64;
    const int h    = blockIdx.y, b = blockIdx.z;

    // ---- one-time Q tile + x_mask stage ----
#pragma unroll
    for (int i = 0; i < 2; i++) {
        const int e = t + i * 256, r = e >> 3, cg = (e & 7) * 8;
        *(uint4*)&Qs[r][cg] =
            *(const uint4*)&Q[((size_t)(b * SEQ + l0 + r)) * D_MODEL + h * HEAD_DIM + cg];
    }
    if (t < 64) xms[t] = xmask[b * SEQ + l0 + t];

    const int rowbase = w * 16 + quad * 4;   // tile-local row of C/D reg 0
    const int arow    = w * 16 + l16;        // tile-local row for A-frags

    float m_i[4] = {-INFINITY, -INFINITY, -INFINITY, -INFINITY};
    float l_i[4] = {0.f, 0.f, 0.f, 0.f};
    f32x4 oacc[4] = {};   // [ct] over d-cols, reg over rows

    for (int s0 = 0; s0 < SEQ; s0 += 64) {
        __syncthreads();  // prev tile consumed (and Q staged, first iter)
#pragma unroll
        for (int i = 0; i < 2; i++) {
            const int e = t + i * 256, r = e >> 3, cg = (e & 7) * 8;
            *(uint4*)&Ks[r][cg] =
                *(const uint4*)&K[((size_t)(b * SEQ + s0 + r)) * D_MODEL + h * HEAD_DIM + cg];
            *(uint4*)&Vs[r][cg] =
                *(const uint4*)&Vt[((size_t)(b * 256 + h * HEAD_DIM + r)) * SEQ + s0 + cg];
        }
#pragma unroll
        for (int i = 0; i < 4; i++) {
            const int e = t + i * 256, r = e >> 4, c4 = (e & 15) * 4;
            *(float4*)&Cs[r][c4] =
                *(const float4*)&comp[((size_t)(b * SEQ) + l0 + r) * SEQ + s0 + c4];
        }
        if (t < 64) sms[t] = smask[b * SEQ + s0 + t];
        __syncthreads();

        // ---- QK^T: 16 rows x 64 cols per wave ----
        f32x4 sacc[4] = {};
#pragma unroll
        for (int kc = 0; kc < 64; kc += 32) {
            const short8 aq = *(const short8*)&Qs[arow][kc + quad * 8];
#pragma unroll
            for (int ct = 0; ct < 4; ct++) {
                const short8 bk = *(const short8*)&Ks[ct * 16 + l16][kc + quad * 8];
                sacc[ct] = __builtin_amdgcn_mfma_f32_16x16x32_bf16(aq, bk, sacc[ct], 0, 0, 0);
            }
        }

        // ---- comp * /8, mask, online softmax ----
        const int sm0 = sms[l16], sm1 = sms[16 + l16], sm2 = sms[32 + l16], sm3 = sms[48 + l16];
        float sc[4][4];
        float rm[4];
#pragma unroll
        for (int reg = 0; reg < 4; reg++) {
            const int lrow = rowbase + reg;
            const bool xm = (xms[lrow] != 0);
            float s0v = sacc[0][reg] * Cs[lrow][l16]      * 0.125f;
            float s1v = sacc[1][reg] * Cs[lrow][16 + l16] * 0.125f;
            float s2v = sacc[2][reg] * Cs[lrow][32 + l16] * 0.125f;
            float s3v = sacc[3][reg] * Cs[lrow][48 + l16] * 0.125f;
            if (xm) {
                if (sm0 == 0) s0v = -1e30f;
                if (sm1 == 0) s1v = -1e30f;
                if (sm2 == 0) s2v = -1e30f;
                if (sm3 == 0) s3v = -1e30f;
            }
            sc[0][reg] = s0v; sc[1][reg] = s1v; sc[2][reg] = s2v; sc[3][reg] = s3v;
            rm[reg] = fmaxf(fmaxf(s0v, s1v), fmaxf(s2v, s3v));
        }
#pragma unroll
        for (int off = 1; off < 16; off <<= 1) {
#pragma unroll
            for (int reg = 0; reg < 4; reg++)
                rm[reg] = fmaxf(rm[reg], __shfl_xor(rm[reg], off, 64));
        }

        float alpha[4], psum[4];
#pragma unroll
        for (int reg = 0; reg < 4; reg++) {
            const float m_new = fmaxf(m_i[reg], rm[reg]);
            alpha[reg] = __expf(m_i[reg] - m_new);
            m_i[reg] = m_new;
            float ps = 0.f;
#pragma unroll
            for (int ct = 0; ct < 4; ct++) {
                const float p = __expf(sc[ct][reg] - m_new);
                ps += p;
                Ps[rowbase + reg][ct * 16 + l16] = f2bf_bits(p);
            }
            psum[reg] = ps;
        }
#pragma unroll
        for (int off = 1; off < 16; off <<= 1) {
#pragma unroll
            for (int reg = 0; reg < 4; reg++)
                psum[reg] += __shfl_xor(psum[reg], off, 64);
        }
#pragma unroll
        for (int reg = 0; reg < 4; reg++)
            l_i[reg] = l_i[reg] * alpha[reg] + psum[reg];
#pragma unroll
        for (int ct = 0; ct < 4; ct++) {
#pragma unroll
            for (int reg = 0; reg < 4; reg++) oacc[ct][reg] *= alpha[reg];
        }

        // ---- PV (wave-local P round-trip; compiler inserts lgkmcnt) ----
#pragma unroll
        for (int kc = 0; kc < 64; kc += 32) {
            const short8 ap = *(const short8*)&Ps[arow][kc + quad * 8];
#pragma unroll
            for (int ct = 0; ct < 4; ct++) {
                const short8 bv = *(const short8*)&Vs[ct * 16 + l16][kc + quad * 8];
                oacc[ct] = __builtin_amdgcn_mfma_f32_16x16x32_bf16(ap, bv, oacc[ct], 0, 0, 0);
            }
        }
    }

    float inv[4];
#pragma unroll
    for (int reg = 0; reg < 4; reg++) inv[reg] = 1.f / l_i[reg];
#pragma unroll
    for (int ct = 0; ct < 4; ct++) {
#pragma unroll
        for (int reg = 0; reg < 4; reg++) {
            const int grow = b * SEQ + l0 + rowbase + reg;
            O[(size_t)grow * D_MODEL + h * HEAD_DIM + ct * 16 + l16] =
                oacc[ct][reg] * inv[reg];
        }
    }
}

// ---------------------------------------------------------------------------
// LayerNorm over rows of 256. Block 256 = one row. Optional residual add.
// ---------------------------------------------------------------------------
template <bool RESID>
__global__ __launch_bounds__(256) void ln_k(
    const float* __restrict__ in, const float* __restrict__ g,
    const float* __restrict__ bta, const float* __restrict__ resid,
    float* __restrict__ out)
{
    const int row = blockIdx.x, t = threadIdx.x;
    const float v = in[(size_t)row * 256 + t];
    float s = v, s2 = v * v;
#pragma unroll
    for (int off = 1; off < 64; off <<= 1) {
        s  += __shfl_xor(s, off, 64);
        s2 += __shfl_xor(s2, off, 64);
    }
    __shared__ float red[2][4];
    const int w = t >> 6, ln = t & 63;
    if (ln == 0) { red[0][w] = s; red[1][w] = s2; }
    __syncthreads();
    s  = red[0][0] + red[0][1] + red[0][2] + red[0][3];
    s2 = red[1][0] + red[1][1] + red[1][2] + red[1][3];
    const float mu  = s * (1.f / 256.f);
    const float var = s2 * (1.f / 256.f) - mu * mu;
    const float r   = rsqrtf(var + 1e-5f);
    float o = (v - mu) * r * g[t] + bta[t];
    if (RESID) o += resid[(size_t)row * 256 + t];
    out[(size_t)row * 256 + t] = o;
}

// ---------------------------------------------------------------------------
extern "C" void kernel_launch(void* const* d_in, const int* in_sizes, int n_in,
                              void* d_out, int out_size, void* d_ws, size_t ws_size,
                              hipStream_t stream)
{
    (void)in_sizes; (void)n_in; (void)out_size; (void)ws_size;
    const float* x      = (const float*)d_in[0];
    const float* source = (const float*)d_in[1];
    const float* x_pe   = (const float*)d_in[2];
    const float* s_pe   = (const float*)d_in[3];
    const int*   x_mask = (const int*)d_in[4];
    const int*   s_mask = (const int*)d_in[5];
    const float* comp   = (const float*)d_in[6];
    const float* Wq     = (const float*)d_in[7];
    const float* Wk     = (const float*)d_in[8];
    const float* Wv     = (const float*)d_in[9];
    const float* Wmerge = (const float*)d_in[10];
    const float* Wmlp1  = (const float*)d_in[11];
    const float* Wmlp2  = (const float*)d_in[12];
    const float* ln1_g  = (const float*)d_in[13];
    const float* ln1_b  = (const float*)d_in[14];
    const float* ln2_g  = (const float*)d_in[15];
    const float* ln2_b  = (const float*)d_in[16];
    float* out = (float*)d_out;
    char*  ws  = (char*)d_ws;

    const size_t MB = 1024 * 1024;
    // region A [0,6MB): bf16 Q,K,Vt; later reused as fp32 Msg1 (4MB)
    ushort* Qb  = (ushort*)(ws + 0 * MB);
    ushort* Kb  = (ushort*)(ws + 2 * MB);
    ushort* VtG = (ushort*)(ws + 4 * MB);
    float*  Ob  = (float*)(ws + 6 * MB);    // region B [6,10): Ob, later M2
    float*  Mg  = (float*)(ws + 10 * MB);   // region C [10,14): Mg, later H head
    float*  Msg1 = (float*)(ws + 0 * MB);
    float*  H    = (float*)(ws + 10 * MB);  // [10,18): overwrites dead Mg
    float*  M2   = (float*)(ws + 6 * MB);

    const dim3 g256(D_MODEL / 64, MROWS / 64);  // (4, 64)
    const dim3 g512(512 / 64, MROWS / 64);      // (8, 64)

    gemm_k<1, false, 1><<<g256, 256, 0, stream>>>(x, x_pe, Wq, Qb, 256, 256, 256);
    gemm_k<1, false, 1><<<g256, 256, 0, stream>>>(source, s_pe, Wk, Kb, 256, 256, 256);
    gemm_k<0, false, 2><<<g256, 256, 0, stream>>>(source, nullptr, Wv, VtG, 256, 256, 256);

    attn_k<<<dim3(SEQ / 64, NHEAD, BSZ), 256, 0, stream>>>(
        Qb, Kb, VtG, comp, x_mask, s_mask, Ob);

    gemm_k<0, false, 0><<<g256, 256, 0, stream>>>(Ob, nullptr, Wmerge, Mg, 256, 256, 256);
    ln_k<false><<<MROWS, 256, 0, stream>>>(Mg, ln1_g, ln1_b, nullptr, Msg1);
    gemm_k<2, true, 0><<<g512, 256, 0, stream>>>(x, Msg1, Wmlp1, H, 512, 512, 256);
    gemm_k<0, false, 0><<<g256, 256, 0, stream>>>(H, nullptr, Wmlp2, M2, 512, 256, 512);
    ln_k<true><<<MROWS, 256, 0, stream>>>(M2, ln2_g, ln2_b, x, out);
}

// Round 3
// 232.199 us; speedup vs baseline: 3.1262x; 1.3837x over previous
//
#include <hip/hip_runtime.h>
#include <cstddef>
#include <math.h>

#define D_MODEL 256
#define NHEAD 4
#define HEAD_DIM 64
#define BSZ 2
#define SEQ 2048
#define MROWS (BSZ * SEQ) /* 4096 */

typedef __attribute__((ext_vector_type(8))) short short8;   // 8 bf16 = 4 VGPRs
typedef __attribute__((ext_vector_type(4))) float f32x4;    // MFMA C/D

__device__ __forceinline__ ushort f2bf_bits(float f) {
    union { float f; unsigned u; } c; c.f = f;
    unsigned u = c.u + 0x7fffu + ((c.u >> 16) & 1u);  // RNE
    return (ushort)(u >> 16);
}
__device__ __forceinline__ unsigned pk2(float lo, float hi) {
    return (unsigned)f2bf_bits(lo) | ((unsigned)f2bf_bits(hi) << 16);
}
__device__ __forceinline__ void store_bf8(ushort* p, float4 a, float4 b) {
    uint4 u = make_uint4(pk2(a.x, a.y), pk2(a.z, a.w), pk2(b.x, b.y), pk2(b.z, b.w));
    *(uint4*)p = u;
}

// ---------------------------------------------------------------------------
// Prep: bf16-ify activations and transpose+bf16-ify weights.
// Blocks [0,512): activations — 8 elems/thread over the 1M-element (4096,256)
// index space shared by x / x_pe / source / source_pe.
// Blocks [512,672): weights — W[K][N] fp32 -> Wt[N][K] bf16, 16 elems/thread.
// ---------------------------------------------------------------------------
__global__ __launch_bounds__(256) void prep_k(
    const float* __restrict__ x, const float* __restrict__ xpe,
    const float* __restrict__ src, const float* __restrict__ spe,
    const float* __restrict__ Wq, const float* __restrict__ Wk,
    const float* __restrict__ Wv, const float* __restrict__ Wm,
    const float* __restrict__ W1, const float* __restrict__ W2,
    ushort* __restrict__ Qin, ushort* __restrict__ Kin,
    ushort* __restrict__ Sb, ushort* __restrict__ Xb,
    ushort* __restrict__ Wqt, ushort* __restrict__ Wkt,
    ushort* __restrict__ Wvt, ushort* __restrict__ Wmt,
    ushort* __restrict__ W1t, ushort* __restrict__ W2t)
{
    const int gb = blockIdx.x;
    if (gb < 512) {
        const int e0 = (gb * 256 + threadIdx.x) * 8;
        const float4 a0 = *(const float4*)&x[e0],   a1 = *(const float4*)&x[e0 + 4];
        const float4 p0 = *(const float4*)&xpe[e0], p1 = *(const float4*)&xpe[e0 + 4];
        const float4 s0 = *(const float4*)&src[e0], s1 = *(const float4*)&src[e0 + 4];
        const float4 q0 = *(const float4*)&spe[e0], q1 = *(const float4*)&spe[e0 + 4];
        store_bf8(&Xb[e0], a0, a1);
        store_bf8(&Qin[e0],
                  make_float4(a0.x + p0.x, a0.y + p0.y, a0.z + p0.z, a0.w + p0.w),
                  make_float4(a1.x + p1.x, a1.y + p1.y, a1.z + p1.z, a1.w + p1.w));
        store_bf8(&Sb[e0], s0, s1);
        store_bf8(&Kin[e0],
                  make_float4(s0.x + q0.x, s0.y + q0.y, s0.z + q0.z, s0.w + q0.w),
                  make_float4(s1.x + q1.x, s1.y + q1.y, s1.z + q1.z, s1.w + q1.w));
    } else {
        const int f0 = ((gb - 512) * 256 + threadIdx.x) * 16;
        const float* in; ushort* out; int Nd, ksh, r;
        if (f0 < 262144) {
            const int w = f0 >> 16; r = f0 & 65535; Nd = 256; ksh = 8;
            in  = (w == 0) ? Wq  : (w == 1) ? Wk  : (w == 2) ? Wv  : Wm;
            out = (w == 0) ? Wqt : (w == 1) ? Wkt : (w == 2) ? Wvt : Wmt;
        } else if (f0 < 524288) { r = f0 - 262144; Nd = 512; ksh = 9; in = W1; out = W1t; }
        else                    { r = f0 - 524288; Nd = 256; ksh = 9; in = W2; out = W2t; }
        const int n = r >> ksh, k = r & ((1 << ksh) - 1);
        ushort tmp[16];
#pragma unroll
        for (int i = 0; i < 16; i++) tmp[i] = f2bf_bits(in[(size_t)(k + i) * Nd + n]);
        *(uint4*)&out[r]     = *(uint4*)&tmp[0];
        *(uint4*)&out[r + 8] = *(uint4*)&tmp[8];
    }
}

// ---------------------------------------------------------------------------
// bf16 MFMA GEMM: C[M x N] = op(A)[M x K] @ Bt^T, A row-major bf16,
// Bt pre-transposed bf16 [N][K]. 64x64 tile, BK=64, 256 thr (4 waves).
// AMODE 0: A=A1 (stride Kdim)    2: A=concat(A1,A2) (each stride 256)
// OMODE 0: fp32 row-major        1: bf16 row-major   2: bf16 V-transposed
//   (OMODE 2: out[(b*256 + n)*2048 + s], m = b*2048 + s)
// MFMA layouts: A[m=l16][k=quad*8+j]; B[k=quad*8+j][n=l16] = Bs[n][k];
// C/D col=l16, row=quad*4+reg.
// ---------------------------------------------------------------------------
template <int AMODE, bool RELU, int OMODE>
__global__ __launch_bounds__(256) void bgemm_k(
    const ushort* __restrict__ A1, const ushort* __restrict__ A2,
    const ushort* __restrict__ Bt, void* __restrict__ Cout,
    int Kdim, int Ndim)
{
    __shared__ __attribute__((aligned(16))) ushort As[64][72];
    __shared__ __attribute__((aligned(16))) ushort Bs[64][72];

    const int t = threadIdx.x, w = t >> 6, lane = t & 63;
    const int quad = lane >> 4, l16 = lane & 15;
    const int m0 = blockIdx.y * 64, n0 = blockIdx.x * 64;
    const int rS = t >> 2, kS = (t & 3) * 16;

    f32x4 acc[4] = {};

    for (int k0 = 0; k0 < Kdim; k0 += 64) {
        const ushort* pa;
        if (AMODE == 2) {
            pa = (k0 < 256) ? &A1[(size_t)(m0 + rS) * 256 + k0 + kS]
                            : &A2[(size_t)(m0 + rS) * 256 + (k0 - 256) + kS];
        } else {
            pa = &A1[(size_t)(m0 + rS) * Kdim + k0 + kS];
        }
        const uint4 va0 = *(const uint4*)pa, va1 = *(const uint4*)(pa + 8);
        const ushort* pb = &Bt[(size_t)(n0 + rS) * Kdim + k0 + kS];
        const uint4 vb0 = *(const uint4*)pb, vb1 = *(const uint4*)(pb + 8);

        __syncthreads();
        *(uint4*)&As[rS][kS] = va0; *(uint4*)&As[rS][kS + 8] = va1;
        *(uint4*)&Bs[rS][kS] = vb0; *(uint4*)&Bs[rS][kS + 8] = vb1;
        __syncthreads();

#pragma unroll
        for (int kc = 0; kc < 64; kc += 32) {
            const short8 aq = *(const short8*)&As[w * 16 + l16][kc + quad * 8];
#pragma unroll
            for (int ct = 0; ct < 4; ct++) {
                const short8 bk = *(const short8*)&Bs[ct * 16 + l16][kc + quad * 8];
                acc[ct] = __builtin_amdgcn_mfma_f32_16x16x32_bf16(aq, bk, acc[ct], 0, 0, 0);
            }
        }
    }

#pragma unroll
    for (int ct = 0; ct < 4; ct++) {
#pragma unroll
        for (int reg = 0; reg < 4; reg++) {
            const int grow = m0 + w * 16 + quad * 4 + reg;
            const int col  = n0 + ct * 16 + l16;
            float v = acc[ct][reg];
            if (RELU) v = fmaxf(v, 0.f);
            if (OMODE == 0) {
                ((float*)Cout)[(size_t)grow * Ndim + col] = v;
            } else if (OMODE == 1) {
                ((ushort*)Cout)[(size_t)grow * Ndim + col] = f2bf_bits(v);
            } else {
                const int b = grow >> 11, s = grow & 2047;
                ((ushort*)Cout)[((size_t)(b * 256 + col)) * 2048 + s] = f2bf_bits(v);
            }
        }
    }
}

// ---------------------------------------------------------------------------
// MFMA flash attention. Grid (SEQ/64, NHEAD, BSZ), block 256 (4 waves).
// comp loaded straight to VGPRs (no LDS) -> 37.5 KB LDS -> 4 blocks/CU.
// Output bf16 row-major.
// ---------------------------------------------------------------------------
__global__ __launch_bounds__(256, 4) void attn_k(
    const ushort* __restrict__ Q, const ushort* __restrict__ K,
    const ushort* __restrict__ Vt, const float* __restrict__ comp,
    const int* __restrict__ xmask, const int* __restrict__ smask,
    ushort* __restrict__ O)
{
    __shared__ __attribute__((aligned(16))) ushort Qs[64][72];
    __shared__ __attribute__((aligned(16))) ushort Ks[64][72];
    __shared__ __attribute__((aligned(16))) ushort Vs[64][72];   // [d][key]
    __shared__ __attribute__((aligned(16))) ushort Ps[64][72];
    __shared__ int xms[64];
    __shared__ int sms[64];

    const int t    = threadIdx.x;
    const int w    = t >> 6;
    const int lane = t & 63;
    const int quad = lane >> 4;
    const int l16  = lane & 15;
    const int l0   = blockIdx.x * 64;
    const int h    = blockIdx.y, b = blockIdx.z;

#pragma unroll
    for (int i = 0; i < 2; i++) {
        const int e = t + i * 256, r = e >> 3, cg = (e & 7) * 8;
        *(uint4*)&Qs[r][cg] =
            *(const uint4*)&Q[((size_t)(b * SEQ + l0 + r)) * D_MODEL + h * HEAD_DIM + cg];
    }
    if (t < 64) xms[t] = xmask[b * SEQ + l0 + t];

    const int rowbase = w * 16 + quad * 4;
    const int arow    = w * 16 + l16;
    const float* crow = comp + ((size_t)b * SEQ + l0 + rowbase) * SEQ;

    float m_i[4] = {-INFINITY, -INFINITY, -INFINITY, -INFINITY};
    float l_i[4] = {0.f, 0.f, 0.f, 0.f};
    f32x4 oacc[4] = {};

    for (int s0 = 0; s0 < SEQ; s0 += 64) {
        __syncthreads();  // prev tile consumed (and Q staged, first iter)
#pragma unroll
        for (int i = 0; i < 2; i++) {
            const int e = t + i * 256, r = e >> 3, cg = (e & 7) * 8;
            *(uint4*)&Ks[r][cg] =
                *(const uint4*)&K[((size_t)(b * SEQ + s0 + r)) * D_MODEL + h * HEAD_DIM + cg];
            *(uint4*)&Vs[r][cg] =
                *(const uint4*)&Vt[((size_t)(b * 256 + h * HEAD_DIM + r)) * SEQ + s0 + cg];
        }
        if (t < 64) sms[t] = smask[b * SEQ + s0 + t];

        // comp gather straight to regs (independent of LDS; overlaps staging)
        float cv[16];
#pragma unroll
        for (int reg = 0; reg < 4; reg++)
#pragma unroll
            for (int ct = 0; ct < 4; ct++)
                cv[reg * 4 + ct] = crow[(size_t)reg * SEQ + s0 + ct * 16 + l16];

        __syncthreads();

        // ---- QK^T ----
        f32x4 sacc[4] = {};
#pragma unroll
        for (int kc = 0; kc < 64; kc += 32) {
            const short8 aq = *(const short8*)&Qs[arow][kc + quad * 8];
#pragma unroll
            for (int ct = 0; ct < 4; ct++) {
                const short8 bk = *(const short8*)&Ks[ct * 16 + l16][kc + quad * 8];
                sacc[ct] = __builtin_amdgcn_mfma_f32_16x16x32_bf16(aq, bk, sacc[ct], 0, 0, 0);
            }
        }

        // ---- scale * comp, mask, online softmax ----
        const int sm0 = sms[l16], sm1 = sms[16 + l16], sm2 = sms[32 + l16], sm3 = sms[48 + l16];
        float sc[4][4];
        float rm[4];
#pragma unroll
        for (int reg = 0; reg < 4; reg++) {
            const bool xm = (xms[rowbase + reg] != 0);
            float s0v = sacc[0][reg] * cv[reg * 4 + 0] * 0.125f;
            float s1v = sacc[1][reg] * cv[reg * 4 + 1] * 0.125f;
            float s2v = sacc[2][reg] * cv[reg * 4 + 2] * 0.125f;
            float s3v = sacc[3][reg] * cv[reg * 4 + 3] * 0.125f;
            if (xm) {
                if (sm0 == 0) s0v = -1e30f;
                if (sm1 == 0) s1v = -1e30f;
                if (sm2 == 0) s2v = -1e30f;
                if (sm3 == 0) s3v = -1e30f;
            }
            sc[0][reg] = s0v; sc[1][reg] = s1v; sc[2][reg] = s2v; sc[3][reg] = s3v;
            rm[reg] = fmaxf(fmaxf(s0v, s1v), fmaxf(s2v, s3v));
        }
#pragma unroll
        for (int off = 1; off < 16; off <<= 1)
#pragma unroll
            for (int reg = 0; reg < 4; reg++)
                rm[reg] = fmaxf(rm[reg], __shfl_xor(rm[reg], off, 64));

        float alpha[4], psum[4];
#pragma unroll
        for (int reg = 0; reg < 4; reg++) {
            const float m_new = fmaxf(m_i[reg], rm[reg]);
            alpha[reg] = __expf(m_i[reg] - m_new);
            m_i[reg] = m_new;
            float ps = 0.f;
#pragma unroll
            for (int ct = 0; ct < 4; ct++) {
                const float p = __expf(sc[ct][reg] - m_new);
                ps += p;
                Ps[rowbase + reg][ct * 16 + l16] = f2bf_bits(p);
            }
            psum[reg] = ps;
        }
#pragma unroll
        for (int off = 1; off < 16; off <<= 1)
#pragma unroll
            for (int reg = 0; reg < 4; reg++)
                psum[reg] += __shfl_xor(psum[reg], off, 64);
#pragma unroll
        for (int reg = 0; reg < 4; reg++)
            l_i[reg] = l_i[reg] * alpha[reg] + psum[reg];
#pragma unroll
        for (int ct = 0; ct < 4; ct++)
#pragma unroll
            for (int reg = 0; reg < 4; reg++) oacc[ct][reg] *= alpha[reg];

        // ---- PV (Ps rows are wave-private; no barrier needed) ----
#pragma unroll
        for (int kc = 0; kc < 64; kc += 32) {
            const short8 ap = *(const short8*)&Ps[arow][kc + quad * 8];
#pragma unroll
            for (int ct = 0; ct < 4; ct++) {
                const short8 bv = *(const short8*)&Vs[ct * 16 + l16][kc + quad * 8];
                oacc[ct] = __builtin_amdgcn_mfma_f32_16x16x32_bf16(ap, bv, oacc[ct], 0, 0, 0);
            }
        }
    }

    float inv[4];
#pragma unroll
    for (int reg = 0; reg < 4; reg++) inv[reg] = 1.f / l_i[reg];
#pragma unroll
    for (int ct = 0; ct < 4; ct++)
#pragma unroll
        for (int reg = 0; reg < 4; reg++) {
            const int grow = b * SEQ + l0 + rowbase + reg;
            O[(size_t)grow * D_MODEL + h * HEAD_DIM + ct * 16 + l16] =
                f2bf_bits(oacc[ct][reg] * inv[reg]);
        }
}

// ---------------------------------------------------------------------------
// LayerNorm over rows of 256. Block 256 = one row.
// ---------------------------------------------------------------------------
template <bool RESID, bool BF16OUT>
__global__ __launch_bounds__(256) void ln_k(
    const float* __restrict__ in, const float* __restrict__ g,
    const float* __restrict__ bta, const float* __restrict__ resid,
    void* __restrict__ out)
{
    const int row = blockIdx.x, t = threadIdx.x;
    const float v = in[(size_t)row * 256 + t];
    float s = v, s2 = v * v;
#pragma unroll
    for (int off = 1; off < 64; off <<= 1) {
        s  += __shfl_xor(s, off, 64);
        s2 += __shfl_xor(s2, off, 64);
    }
    __shared__ float red[2][4];
    const int w = t >> 6, ln = t & 63;
    if (ln == 0) { red[0][w] = s; red[1][w] = s2; }
    __syncthreads();
    s  = red[0][0] + red[0][1] + red[0][2] + red[0][3];
    s2 = red[1][0] + red[1][1] + red[1][2] + red[1][3];
    const float mu  = s * (1.f / 256.f);
    const float var = s2 * (1.f / 256.f) - mu * mu;
    const float r   = rsqrtf(var + 1e-5f);
    float o = (v - mu) * r * g[t] + bta[t];
    if (RESID) o += resid[(size_t)row * 256 + t];
    if (BF16OUT) ((ushort*)out)[(size_t)row * 256 + t] = f2bf_bits(o);
    else         ((float*)out)[(size_t)row * 256 + t] = o;
}

// ---------------------------------------------------------------------------
extern "C" void kernel_launch(void* const* d_in, const int* in_sizes, int n_in,
                              void* d_out, int out_size, void* d_ws, size_t ws_size,
                              hipStream_t stream)
{
    (void)in_sizes; (void)n_in; (void)out_size; (void)ws_size;
    const float* x      = (const float*)d_in[0];
    const float* source = (const float*)d_in[1];
    const float* x_pe   = (const float*)d_in[2];
    const float* s_pe   = (const float*)d_in[3];
    const int*   x_mask = (const int*)d_in[4];
    const int*   s_mask = (const int*)d_in[5];
    const float* comp   = (const float*)d_in[6];
    const float* Wq     = (const float*)d_in[7];
    const float* Wk     = (const float*)d_in[8];
    const float* Wv     = (const float*)d_in[9];
    const float* Wmerge = (const float*)d_in[10];
    const float* Wmlp1  = (const float*)d_in[11];
    const float* Wmlp2  = (const float*)d_in[12];
    const float* ln1_g  = (const float*)d_in[13];
    const float* ln1_b  = (const float*)d_in[14];
    const float* ln2_g  = (const float*)d_in[15];
    const float* ln2_b  = (const float*)d_in[16];
    float* out = (float*)d_out;
    char*  ws  = (char*)d_ws;

    const size_t MB = 1024 * 1024;
    ushort* Qin   = (ushort*)(ws + 0 * MB);   // dead after Q gemm
    ushort* Kin   = (ushort*)(ws + 2 * MB);   // dead after K gemm
    ushort* Sb    = (ushort*)(ws + 4 * MB);   // dead after V gemm
    ushort* Xb    = (ushort*)(ws + 6 * MB);   // live until mlp1
    ushort* Qb    = (ushort*)(ws + 8 * MB);
    ushort* Kb    = (ushort*)(ws + 10 * MB);
    ushort* VtG   = (ushort*)(ws + 12 * MB);
    ushort* Obf   = (ushort*)(ws + 0 * MB);   // reuse Qin
    float*  Mg    = (float*)(ws + 2 * MB);    // reuse Kin+Sb (4 MB)
    ushort* Msg1b = (ushort*)(ws + 8 * MB);   // reuse Qb
    ushort* H     = (ushort*)(ws + 10 * MB);  // reuse Kb+Vt (4 MB)
    float*  M2    = (float*)(ws + 14 * MB);   // 4 MB
    ushort* Wqt   = (ushort*)(ws + 18 * MB);
    ushort* Wkt   = (ushort*)(ws + 18 * MB + 128 * 1024);
    ushort* Wvt   = (ushort*)(ws + 18 * MB + 256 * 1024);
    ushort* Wmt   = (ushort*)(ws + 18 * MB + 384 * 1024);
    ushort* W1t   = (ushort*)(ws + 18 * MB + 512 * 1024);
    ushort* W2t   = (ushort*)(ws + 19 * MB);  // ends 19.25 MB

    const dim3 g256(4, 64), g512(8, 64);

    prep_k<<<672, 256, 0, stream>>>(x, x_pe, source, s_pe,
        Wq, Wk, Wv, Wmerge, Wmlp1, Wmlp2,
        Qin, Kin, Sb, Xb, Wqt, Wkt, Wvt, Wmt, W1t, W2t);

    bgemm_k<0, false, 1><<<g256, 256, 0, stream>>>(Qin, nullptr, Wqt, Qb, 256, 256);
    bgemm_k<0, false, 1><<<g256, 256, 0, stream>>>(Kin, nullptr, Wkt, Kb, 256, 256);
    bgemm_k<0, false, 2><<<g256, 256, 0, stream>>>(Sb, nullptr, Wvt, VtG, 256, 256);

    attn_k<<<dim3(SEQ / 64, NHEAD, BSZ), 256, 0, stream>>>(
        Qb, Kb, VtG, comp, x_mask, s_mask, Obf);

    bgemm_k<0, false, 0><<<g256, 256, 0, stream>>>(Obf, nullptr, Wmt, Mg, 256, 256);
    ln_k<false, true><<<MROWS, 256, 0, stream>>>(Mg, ln1_g, ln1_b, nullptr, Msg1b);
    bgemm_k<2, true, 1><<<g512, 256, 0, stream>>>(Xb, Msg1b, W1t, H, 512, 512);
    bgemm_k<0, false, 0><<<g256, 256, 0, stream>>>(H, nullptr, W2t, M2, 512, 256);
    ln_k<true, false><<<MROWS, 256, 0, stream>>>(M2, ln2_g, ln2_b, x, out);
}

// Round 4
// 220.697 us; speedup vs baseline: 3.2891x; 1.0521x over previous
//
#include <hip/hip_runtime.h>
#include <cstddef>
#include <math.h>

#define D_MODEL 256
#define NHEAD 4
#define HEAD_DIM 64
#define BSZ 2
#define SEQ 2048
#define MROWS (BSZ * SEQ) /* 4096 */
#define NSPLIT 4
#define SCHUNK (SEQ / NSPLIT) /* 512 */

typedef __attribute__((ext_vector_type(8))) short short8;   // 8 bf16 = 4 VGPRs
typedef __attribute__((ext_vector_type(4))) float f32x4;    // MFMA C/D

__device__ __forceinline__ ushort f2bf_bits(float f) {
    union { float f; unsigned u; } c; c.f = f;
    unsigned u = c.u + 0x7fffu + ((c.u >> 16) & 1u);  // RNE
    return (ushort)(u >> 16);
}
__device__ __forceinline__ float bf2f(ushort u) {
    union { unsigned u; float f; } c; c.u = (unsigned)u << 16;
    return c.f;
}
__device__ __forceinline__ unsigned pk2(float lo, float hi) {
    return (unsigned)f2bf_bits(lo) | ((unsigned)f2bf_bits(hi) << 16);
}
__device__ __forceinline__ void store_bf8(ushort* p, float4 a, float4 b) {
    uint4 u = make_uint4(pk2(a.x, a.y), pk2(a.z, a.w), pk2(b.x, b.y), pk2(b.z, b.w));
    *(uint4*)p = u;
}

// ---------------------------------------------------------------------------
// Prep: bf16-ify activations and transpose+bf16-ify weights.
// ---------------------------------------------------------------------------
__global__ __launch_bounds__(256) void prep_k(
    const float* __restrict__ x, const float* __restrict__ xpe,
    const float* __restrict__ src, const float* __restrict__ spe,
    const float* __restrict__ Wq, const float* __restrict__ Wk,
    const float* __restrict__ Wv, const float* __restrict__ Wm,
    const float* __restrict__ W1, const float* __restrict__ W2,
    ushort* __restrict__ Qin, ushort* __restrict__ Kin,
    ushort* __restrict__ Sb, ushort* __restrict__ Xb,
    ushort* __restrict__ Wqt, ushort* __restrict__ Wkt,
    ushort* __restrict__ Wvt, ushort* __restrict__ Wmt,
    ushort* __restrict__ W1t, ushort* __restrict__ W2t)
{
    const int gb = blockIdx.x;
    if (gb < 512) {
        const int e0 = (gb * 256 + threadIdx.x) * 8;
        const float4 a0 = *(const float4*)&x[e0],   a1 = *(const float4*)&x[e0 + 4];
        const float4 p0 = *(const float4*)&xpe[e0], p1 = *(const float4*)&xpe[e0 + 4];
        const float4 s0 = *(const float4*)&src[e0], s1 = *(const float4*)&src[e0 + 4];
        const float4 q0 = *(const float4*)&spe[e0], q1 = *(const float4*)&spe[e0 + 4];
        store_bf8(&Xb[e0], a0, a1);
        store_bf8(&Qin[e0],
                  make_float4(a0.x + p0.x, a0.y + p0.y, a0.z + p0.z, a0.w + p0.w),
                  make_float4(a1.x + p1.x, a1.y + p1.y, a1.z + p1.z, a1.w + p1.w));
        store_bf8(&Sb[e0], s0, s1);
        store_bf8(&Kin[e0],
                  make_float4(s0.x + q0.x, s0.y + q0.y, s0.z + q0.z, s0.w + q0.w),
                  make_float4(s1.x + q1.x, s1.y + q1.y, s1.z + q1.z, s1.w + q1.w));
    } else {
        const int f0 = ((gb - 512) * 256 + threadIdx.x) * 16;
        const float* in; ushort* out; int Nd, ksh, r;
        if (f0 < 262144) {
            const int w = f0 >> 16; r = f0 & 65535; Nd = 256; ksh = 8;
            in  = (w == 0) ? Wq  : (w == 1) ? Wk  : (w == 2) ? Wv  : Wm;
            out = (w == 0) ? Wqt : (w == 1) ? Wkt : (w == 2) ? Wvt : Wmt;
        } else if (f0 < 524288) { r = f0 - 262144; Nd = 512; ksh = 9; in = W1; out = W1t; }
        else                    { r = f0 - 524288; Nd = 256; ksh = 9; in = W2; out = W2t; }
        const int n = r >> ksh, k = r & ((1 << ksh) - 1);
        ushort tmp[16];
#pragma unroll
        for (int i = 0; i < 16; i++) tmp[i] = f2bf_bits(in[(size_t)(k + i) * Nd + n]);
        *(uint4*)&out[r]     = *(uint4*)&tmp[0];
        *(uint4*)&out[r + 8] = *(uint4*)&tmp[8];
    }
}

// ---------------------------------------------------------------------------
// Direct-global MFMA GEMM (no LDS, no barriers). C = op(A) @ Bt^T.
// Block 256 = 4 waves; wave w: rows [m0+w*16, +16), cols [n0, n0+64).
// Fragments loaded straight from global; Bt slices live in L1/L2.
// AMODE 0: A=A1 (stride KD)      2: A=concat(A1,A2) (each stride 256)
// OMODE 0: fp32 row-major        1: bf16 row-major
// ---------------------------------------------------------------------------
template <int AMODE, bool RELU, int OMODE, int KD, int ND>
__global__ __launch_bounds__(256) void bgemm_k(
    const ushort* __restrict__ A1, const ushort* __restrict__ A2,
    const ushort* __restrict__ Bt, void* __restrict__ Cout)
{
    const int t = threadIdx.x, w = t >> 6, lane = t & 63;
    const int quad = lane >> 4, l16 = lane & 15;
    const int m0 = blockIdx.y * 64, n0 = blockIdx.x * 64;
    const int arow = m0 + w * 16 + l16;

    f32x4 acc[4] = {};

#pragma unroll
    for (int k0 = 0; k0 < KD; k0 += 32) {
        const ushort* pa;
        if (AMODE == 2) {
            pa = (k0 < 256) ? &A1[(size_t)arow * 256 + k0 + quad * 8]
                            : &A2[(size_t)arow * 256 + (k0 - 256) + quad * 8];
        } else {
            pa = &A1[(size_t)arow * KD + k0 + quad * 8];
        }
        const short8 aq = *(const short8*)pa;
#pragma unroll
        for (int ct = 0; ct < 4; ct++) {
            const short8 bk =
                *(const short8*)&Bt[(size_t)(n0 + ct * 16 + l16) * KD + k0 + quad * 8];
            acc[ct] = __builtin_amdgcn_mfma_f32_16x16x32_bf16(aq, bk, acc[ct], 0, 0, 0);
        }
    }

#pragma unroll
    for (int ct = 0; ct < 4; ct++) {
#pragma unroll
        for (int reg = 0; reg < 4; reg++) {
            const int grow = m0 + w * 16 + quad * 4 + reg;
            const int col  = n0 + ct * 16 + l16;
            float v = acc[ct][reg];
            if (RELU) v = fmaxf(v, 0.f);
            if (OMODE == 0) ((float*)Cout)[(size_t)grow * ND + col] = v;
            else            ((ushort*)Cout)[(size_t)grow * ND + col] = f2bf_bits(v);
        }
    }
}

// ---------------------------------------------------------------------------
// Fused Q/K/V projections (z selects), direct-global, K=256.
// z==2 writes V transposed: out[(b*256 + n)*2048 + s].
// ---------------------------------------------------------------------------
__global__ __launch_bounds__(256) void qkv_k(
    const ushort* __restrict__ Qin, const ushort* __restrict__ Kin,
    const ushort* __restrict__ Sb,
    const ushort* __restrict__ Wqt, const ushort* __restrict__ Wkt,
    const ushort* __restrict__ Wvt,
    ushort* __restrict__ Qb, ushort* __restrict__ Kb, ushort* __restrict__ VtG)
{
    const int z = blockIdx.z;
    const ushort* A  = (z == 0) ? Qin : (z == 1) ? Kin : Sb;
    const ushort* Bt = (z == 0) ? Wqt : (z == 1) ? Wkt : Wvt;
    ushort* out      = (z == 0) ? Qb  : (z == 1) ? Kb  : VtG;

    const int t = threadIdx.x, w = t >> 6, lane = t & 63;
    const int quad = lane >> 4, l16 = lane & 15;
    const int m0 = blockIdx.y * 64, n0 = blockIdx.x * 64;
    const int arow = m0 + w * 16 + l16;

    f32x4 acc[4] = {};
#pragma unroll
    for (int k0 = 0; k0 < 256; k0 += 32) {
        const short8 aq = *(const short8*)&A[(size_t)arow * 256 + k0 + quad * 8];
#pragma unroll
        for (int ct = 0; ct < 4; ct++) {
            const short8 bk =
                *(const short8*)&Bt[(size_t)(n0 + ct * 16 + l16) * 256 + k0 + quad * 8];
            acc[ct] = __builtin_amdgcn_mfma_f32_16x16x32_bf16(aq, bk, acc[ct], 0, 0, 0);
        }
    }

#pragma unroll
    for (int ct = 0; ct < 4; ct++) {
#pragma unroll
        for (int reg = 0; reg < 4; reg++) {
            const int grow = m0 + w * 16 + quad * 4 + reg;
            const int col  = n0 + ct * 16 + l16;
            const ushort v = f2bf_bits(acc[ct][reg]);
            if (z < 2) {
                out[(size_t)grow * 256 + col] = v;
            } else {
                const int b = grow >> 11, s = grow & 2047;
                out[((size_t)(b * 256 + col)) * 2048 + s] = v;
            }
        }
    }
}

// ---------------------------------------------------------------------------
// Split-S MFMA flash attention. Grid (SEQ/64, NHEAD, BSZ*NSPLIT), block 256.
// Each block: 64 q-rows x one 512-key chunk; writes unnormalized O (bf16)
// and per-row (m,l) fp32 partials.
// ---------------------------------------------------------------------------
__global__ __launch_bounds__(256, 4) void attn_k(
    const ushort* __restrict__ Q, const ushort* __restrict__ K,
    const ushort* __restrict__ Vt, const float* __restrict__ comp,
    const int* __restrict__ xmask, const int* __restrict__ smask,
    ushort* __restrict__ Opart, float2* __restrict__ ml)
{
    __shared__ __attribute__((aligned(16))) ushort Qs[64][72];
    __shared__ __attribute__((aligned(16))) ushort Ks[64][72];
    __shared__ __attribute__((aligned(16))) ushort Vs[64][72];   // [d][key]
    __shared__ __attribute__((aligned(16))) ushort Ps[64][72];
    __shared__ int xms[64];
    __shared__ int sms[64];

    const int t    = threadIdx.x;
    const int w    = t >> 6;
    const int lane = t & 63;
    const int quad = lane >> 4;
    const int l16  = lane & 15;
    const int l0   = blockIdx.x * 64;
    const int h    = blockIdx.y;
    const int b    = blockIdx.z >> 2;
    const int sc   = blockIdx.z & 3;
    const int sbeg = sc * SCHUNK;

#pragma unroll
    for (int i = 0; i < 2; i++) {
        const int e = t + i * 256, r = e >> 3, cg = (e & 7) * 8;
        *(uint4*)&Qs[r][cg] =
            *(const uint4*)&Q[((size_t)(b * SEQ + l0 + r)) * D_MODEL + h * HEAD_DIM + cg];
    }
    if (t < 64) xms[t] = xmask[b * SEQ + l0 + t];

    const int rowbase = w * 16 + quad * 4;
    const int arow    = w * 16 + l16;
    const float* crow = comp + ((size_t)b * SEQ + l0 + rowbase) * SEQ;

    float m_i[4] = {-INFINITY, -INFINITY, -INFINITY, -INFINITY};
    float l_i[4] = {0.f, 0.f, 0.f, 0.f};
    f32x4 oacc[4] = {};

    for (int s0 = sbeg; s0 < sbeg + SCHUNK; s0 += 64) {
        __syncthreads();
#pragma unroll
        for (int i = 0; i < 2; i++) {
            const int e = t + i * 256, r = e >> 3, cg = (e & 7) * 8;
            *(uint4*)&Ks[r][cg] =
                *(const uint4*)&K[((size_t)(b * SEQ + s0 + r)) * D_MODEL + h * HEAD_DIM + cg];
            *(uint4*)&Vs[r][cg] =
                *(const uint4*)&Vt[((size_t)(b * 256 + h * HEAD_DIM + r)) * SEQ + s0 + cg];
        }
        if (t < 64) sms[t] = smask[b * SEQ + s0 + t];

        float cv[16];
#pragma unroll
        for (int reg = 0; reg < 4; reg++)
#pragma unroll
            for (int ct = 0; ct < 4; ct++)
                cv[reg * 4 + ct] = crow[(size_t)reg * SEQ + s0 + ct * 16 + l16];

        __syncthreads();

        // ---- QK^T ----
        f32x4 sacc[4] = {};
#pragma unroll
        for (int kc = 0; kc < 64; kc += 32) {
            const short8 aq = *(const short8*)&Qs[arow][kc + quad * 8];
#pragma unroll
            for (int ct = 0; ct < 4; ct++) {
                const short8 bk = *(const short8*)&Ks[ct * 16 + l16][kc + quad * 8];
                sacc[ct] = __builtin_amdgcn_mfma_f32_16x16x32_bf16(aq, bk, sacc[ct], 0, 0, 0);
            }
        }

        // ---- scale * comp, mask, online softmax ----
        const int sm0 = sms[l16], sm1 = sms[16 + l16], sm2 = sms[32 + l16], sm3 = sms[48 + l16];
        float scv[4][4];
        float rm[4];
#pragma unroll
        for (int reg = 0; reg < 4; reg++) {
            const bool xm = (xms[rowbase + reg] != 0);
            float s0v = sacc[0][reg] * cv[reg * 4 + 0] * 0.125f;
            float s1v = sacc[1][reg] * cv[reg * 4 + 1] * 0.125f;
            float s2v = sacc[2][reg] * cv[reg * 4 + 2] * 0.125f;
            float s3v = sacc[3][reg] * cv[reg * 4 + 3] * 0.125f;
            if (xm) {
                if (sm0 == 0) s0v = -1e30f;
                if (sm1 == 0) s1v = -1e30f;
                if (sm2 == 0) s2v = -1e30f;
                if (sm3 == 0) s3v = -1e30f;
            }
            scv[0][reg] = s0v; scv[1][reg] = s1v; scv[2][reg] = s2v; scv[3][reg] = s3v;
            rm[reg] = fmaxf(fmaxf(s0v, s1v), fmaxf(s2v, s3v));
        }
#pragma unroll
        for (int off = 1; off < 16; off <<= 1)
#pragma unroll
            for (int reg = 0; reg < 4; reg++)
                rm[reg] = fmaxf(rm[reg], __shfl_xor(rm[reg], off, 64));

        float alpha[4], psum[4];
#pragma unroll
        for (int reg = 0; reg < 4; reg++) {
            const float m_new = fmaxf(m_i[reg], rm[reg]);
            alpha[reg] = __expf(m_i[reg] - m_new);
            m_i[reg] = m_new;
            float ps = 0.f;
#pragma unroll
            for (int ct = 0; ct < 4; ct++) {
                // guard: fully-masked tiles contribute 0 (not exp(0))
                const float p = (scv[ct][reg] >= -1e29f) ? __expf(scv[ct][reg] - m_new) : 0.f;
                ps += p;
                Ps[rowbase + reg][ct * 16 + l16] = f2bf_bits(p);
            }
            psum[reg] = ps;
        }
#pragma unroll
        for (int off = 1; off < 16; off <<= 1)
#pragma unroll
            for (int reg = 0; reg < 4; reg++)
                psum[reg] += __shfl_xor(psum[reg], off, 64);
#pragma unroll
        for (int reg = 0; reg < 4; reg++)
            l_i[reg] = l_i[reg] * alpha[reg] + psum[reg];
#pragma unroll
        for (int ct = 0; ct < 4; ct++)
#pragma unroll
            for (int reg = 0; reg < 4; reg++) oacc[ct][reg] *= alpha[reg];

        // ---- PV (Ps rows are wave-private; no barrier needed) ----
#pragma unroll
        for (int kc = 0; kc < 64; kc += 32) {
            const short8 ap = *(const short8*)&Ps[arow][kc + quad * 8];
#pragma unroll
            for (int ct = 0; ct < 4; ct++) {
                const short8 bv = *(const short8*)&Vs[ct * 16 + l16][kc + quad * 8];
                oacc[ct] = __builtin_amdgcn_mfma_f32_16x16x32_bf16(ap, bv, oacc[ct], 0, 0, 0);
            }
        }
    }

    // ---- write partials (unnormalized O, and per-row m/l) ----
#pragma unroll
    for (int ct = 0; ct < 4; ct++)
#pragma unroll
        for (int reg = 0; reg < 4; reg++) {
            const int grow = b * SEQ + l0 + rowbase + reg;
            Opart[((size_t)sc * MROWS + grow) * D_MODEL + h * HEAD_DIM + ct * 16 + l16] =
                f2bf_bits(oacc[ct][reg]);
        }
    if (l16 == 0) {
#pragma unroll
        for (int reg = 0; reg < 4; reg++) {
            const int grow = b * SEQ + l0 + rowbase + reg;
            ml[((size_t)sc * MROWS + grow) * NHEAD + h] = make_float2(m_i[reg], l_i[reg]);
        }
    }
}

// ---------------------------------------------------------------------------
// Combine split-S partials: O = (sum_c e^{m_c-M} O_c) / (sum_c e^{m_c-M} l_c)
// ---------------------------------------------------------------------------
__global__ __launch_bounds__(256) void amerge_k(
    const ushort* __restrict__ Opart, const float2* __restrict__ ml,
    ushort* __restrict__ Obf)
{
    const int row = blockIdx.x, t = threadIdx.x, h = t >> 6;
    float mm[NSPLIT], llv[NSPLIT];
    float M = -INFINITY;
#pragma unroll
    for (int c = 0; c < NSPLIT; c++) {
        const float2 v = ml[((size_t)c * MROWS + row) * NHEAD + h];
        mm[c] = v.x; llv[c] = v.y;
        M = fmaxf(M, v.x);
    }
    float num = 0.f, den = 0.f;
#pragma unroll
    for (int c = 0; c < NSPLIT; c++) {
        const float e = __expf(mm[c] - M);
        den += llv[c] * e;
        num += bf2f(Opart[((size_t)c * MROWS + row) * D_MODEL + t]) * e;
    }
    Obf[(size_t)row * D_MODEL + t] = f2bf_bits(num / den);
}

// ---------------------------------------------------------------------------
// LayerNorm over rows of 256. Block 256 = one row.
// ---------------------------------------------------------------------------
template <bool RESID, bool BF16OUT>
__global__ __launch_bounds__(256) void ln_k(
    const float* __restrict__ in, const float* __restrict__ g,
    const float* __restrict__ bta, const float* __restrict__ resid,
    void* __restrict__ out)
{
    const int row = blockIdx.x, t = threadIdx.x;
    const float v = in[(size_t)row * 256 + t];
    float s = v, s2 = v * v;
#pragma unroll
    for (int off = 1; off < 64; off <<= 1) {
        s  += __shfl_xor(s, off, 64);
        s2 += __shfl_xor(s2, off, 64);
    }
    __shared__ float red[2][4];
    const int w = t >> 6, ln = t & 63;
    if (ln == 0) { red[0][w] = s; red[1][w] = s2; }
    __syncthreads();
    s  = red[0][0] + red[0][1] + red[0][2] + red[0][3];
    s2 = red[1][0] + red[1][1] + red[1][2] + red[1][3];
    const float mu  = s * (1.f / 256.f);
    const float var = s2 * (1.f / 256.f) - mu * mu;
    const float r   = rsqrtf(var + 1e-5f);
    float o = (v - mu) * r * g[t] + bta[t];
    if (RESID) o += resid[(size_t)row * 256 + t];
    if (BF16OUT) ((ushort*)out)[(size_t)row * 256 + t] = f2bf_bits(o);
    else         ((float*)out)[(size_t)row * 256 + t] = o;
}

// ---------------------------------------------------------------------------
extern "C" void kernel_launch(void* const* d_in, const int* in_sizes, int n_in,
                              void* d_out, int out_size, void* d_ws, size_t ws_size,
                              hipStream_t stream)
{
    (void)in_sizes; (void)n_in; (void)out_size; (void)ws_size;
    const float* x      = (const float*)d_in[0];
    const float* source = (const float*)d_in[1];
    const float* x_pe   = (const float*)d_in[2];
    const float* s_pe   = (const float*)d_in[3];
    const int*   x_mask = (const int*)d_in[4];
    const int*   s_mask = (const int*)d_in[5];
    const float* comp   = (const float*)d_in[6];
    const float* Wq     = (const float*)d_in[7];
    const float* Wk     = (const float*)d_in[8];
    const float* Wv     = (const float*)d_in[9];
    const float* Wmerge = (const float*)d_in[10];
    const float* Wmlp1  = (const float*)d_in[11];
    const float* Wmlp2  = (const float*)d_in[12];
    const float* ln1_g  = (const float*)d_in[13];
    const float* ln1_b  = (const float*)d_in[14];
    const float* ln2_g  = (const float*)d_in[15];
    const float* ln2_b  = (const float*)d_in[16];
    float* out = (float*)d_out;
    char*  ws  = (char*)d_ws;

    const size_t MB = 1024 * 1024;
    // live-range packed layout (23.25 MB total):
    ushort* Qin   = (ushort*)(ws + 0 * MB);    // dead after qkv
    float2* ml    = (float2*)(ws + 0 * MB);    // 512 KB, written by attn
    ushort* Kin   = (ushort*)(ws + 2 * MB);    // dead after qkv
    ushort* Obf   = (ushort*)(ws + 2 * MB);    // written by amerge
    ushort* Sb    = (ushort*)(ws + 4 * MB);    // dead after qkv
    ushort* Xb    = (ushort*)(ws + 6 * MB);    // live until mlp1
    ushort* Qb    = (ushort*)(ws + 8 * MB);    // dead after attn
    ushort* Msg1b = (ushort*)(ws + 8 * MB);    // written by ln1
    ushort* Kb    = (ushort*)(ws + 10 * MB);   // dead after attn
    ushort* H     = (ushort*)(ws + 10 * MB);   // 4 MB, written by mlp1
    ushort* VtG   = (ushort*)(ws + 12 * MB);   // dead after attn
    ushort* Opart = (ushort*)(ws + 14 * MB);   // 8 MB bf16, dead after amerge
    float*  Mg    = (float*)(ws + 14 * MB);    // 4 MB, written by merge-gemm
    float*  M2    = (float*)(ws + 18 * MB);    // 4 MB, written by mlp2
    ushort* Wqt   = (ushort*)(ws + 22 * MB);
    ushort* Wkt   = (ushort*)(ws + 22 * MB + 128 * 1024);
    ushort* Wvt   = (ushort*)(ws + 22 * MB + 256 * 1024);
    ushort* Wmt   = (ushort*)(ws + 22 * MB + 384 * 1024);
    ushort* W1t   = (ushort*)(ws + 22 * MB + 512 * 1024);
    ushort* W2t   = (ushort*)(ws + 23 * MB);   // ends 23.25 MB

    prep_k<<<672, 256, 0, stream>>>(x, x_pe, source, s_pe,
        Wq, Wk, Wv, Wmerge, Wmlp1, Wmlp2,
        Qin, Kin, Sb, Xb, Wqt, Wkt, Wvt, Wmt, W1t, W2t);

    qkv_k<<<dim3(4, 64, 3), 256, 0, stream>>>(Qin, Kin, Sb, Wqt, Wkt, Wvt, Qb, Kb, VtG);

    attn_k<<<dim3(SEQ / 64, NHEAD, BSZ * NSPLIT), 256, 0, stream>>>(
        Qb, Kb, VtG, comp, x_mask, s_mask, Opart, ml);

    amerge_k<<<MROWS, 256, 0, stream>>>(Opart, ml, Obf);

    bgemm_k<0, false, 0, 256, 256><<<dim3(4, 64), 256, 0, stream>>>(Obf, nullptr, Wmt, Mg);
    ln_k<false, true><<<MROWS, 256, 0, stream>>>(Mg, ln1_g, ln1_b, nullptr, Msg1b);
    bgemm_k<2, true, 1, 512, 512><<<dim3(8, 64), 256, 0, stream>>>(Xb, Msg1b, W1t, H);
    bgemm_k<0, false, 0, 512, 256><<<dim3(4, 64), 256, 0, stream>>>(H, nullptr, W2t, M2);
    ln_k<true, false><<<MROWS, 256, 0, stream>>>(M2, ln2_g, ln2_b, x, out);
}